// Round 9
// baseline (14612.775 us; speedup 1.0000x reference)
//
#include <hip/hip_runtime.h>
#include <stdint.h>

typedef unsigned short u16;
typedef __attribute__((ext_vector_type(8))) short short8v;
typedef __attribute__((ext_vector_type(4))) float f32x4;

// output layout (floats): out(8,1022,1024) | h_n(2,8,512) | c_n(2,8,512)
#define OUT_HN   8372224
#define OUT_CN   8380416

// ws layout (bytes) — total 25,214,976 B
#define WS_WIH0  0
#define WS_WIH1  (WS_WIH0 + 2097152)
#define WS_WHH0  (WS_WIH1 + 2097152)
#define WS_WHH1  (WS_WHH0 + 2097152)
#define WS_HSB0  (WS_WHH1 + 2097152)        // 1025*8*512 bf16 = 8,396,800 B
#define WS_HSB1  (WS_HSB0 + 8396800)
#define WS_CSB   (WS_HSB1 + 8396800)        // 2*8*512 f32 = 32,768 B

__device__ __forceinline__ u16 f2bf(float f) {
  uint32_t u = __float_as_uint(f);
  u += 0x7FFFu + ((u >> 16) & 1u);
  return (u16)(u >> 16);
}
__device__ __forceinline__ float bf2f(u16 v) {
  return __uint_as_float(((uint32_t)v) << 16);
}
__device__ __forceinline__ short8v cvtx8(const float* p) {
  float4 a = *(const float4*)p;
  float4 b = *(const float4*)(p + 4);
  short8v r;
  r[0] = (short)f2bf(a.x); r[1] = (short)f2bf(a.y);
  r[2] = (short)f2bf(a.z); r[3] = (short)f2bf(a.w);
  r[4] = (short)f2bf(b.x); r[5] = (short)f2bf(b.y);
  r[6] = (short)f2bf(b.z); r[7] = (short)f2bf(b.w);
  return r;
}

__global__ void k_f2bf(const float* __restrict__ src, u16* __restrict__ dst, int n) {
  int i = blockIdx.x * blockDim.x + threadIdx.x;
  int stride = gridDim.x * blockDim.x;
  for (; i < n; i += stride) dst[i] = f2bf(src[i]);
}

// zero h col 0 (both dirs) and c state; ws is 0xAA-poisoned otherwise
__global__ void k_zero(u16* h0, u16* h1, float* c) {
  int i = blockIdx.x * blockDim.x + threadIdx.x;   // 8192 threads
  if (i < 4096) { h0[i] = 0; h1[i] = 0; }
  if (i < 8192) c[i] = 0.f;
}

// One LSTM time step, both directions. grid = 32 blocks x 256 threads.
// blocks 0..15: forward, 16..31: backward. Each WG owns 32 hidden units.
// Wave w = gate w (i,f,g,o). Cross-step ordering via kernel boundaries
// (stream order) — no device-side inter-WG sync of any kind.
__launch_bounds__(256, 1)
__global__ void k_step(const float* __restrict__ xf,
                       const u16* __restrict__ wih0, const u16* __restrict__ wih1,
                       const u16* __restrict__ whh0, const u16* __restrict__ whh1,
                       const float* __restrict__ bias0, const float* __restrict__ bias1,
                       u16* hsb0, u16* hsb1, float* csb, float* out, int step)
{
  const int tid  = threadIdx.x;
  const int wid  = tid >> 6;     // wave = gate
  const int lane = tid & 63;
  const int dir  = blockIdx.x >> 4;
  const int wg   = blockIdx.x & 15;
  const int jbase = wg * 32;

  const u16*  wih  = dir ? wih1  : wih0;
  const u16*  whh  = dir ? whh1  : whh0;
  const float* bias = dir ? bias1 : bias0;
  u16* hsb = dir ? hsb1 : hsb0;

  __shared__ float zL[4 * 8 * 32];   // [gate][b][jj]

  // B-fragments (ws-staged bf16): lane holds
  // W[row = g*512 + jbase + nt*16 + (lane&15)][k = kt*32 + (lane>>4)*8 .. +8]
  short8v bih[2][16], bhh[2][16];
  {
    const int rr = lane & 15;
    const int ko = (lane >> 4) * 8;
    #pragma unroll
    for (int nt = 0; nt < 2; ++nt) {
      const int row = wid * 512 + jbase + nt * 16 + rr;
      #pragma unroll
      for (int kt = 0; kt < 16; ++kt) {
        bih[nt][kt] = *(const short8v*)(wih + (size_t)row * 512 + kt * 32 + ko);
        bhh[nt][kt] = *(const short8v*)(whh + (size_t)row * 512 + kt * 32 + ko);
      }
    }
  }

  // A-fragment: row = lane&7 (lanes 8..15 duplicate rows 0..7; their D rows
  // are never stored), k = (lane>>4)*8
  const int rowc = lane & 7;
  const int ako  = (lane >> 4) * 8;

  const f32x4 fzero = {0.f, 0.f, 0.f, 0.f};
  f32x4 acc0 = fzero, acc1 = fzero;

  // x-projection: x column t' (f32 -> bf16 in-register)
  {
    const int tn = dir ? (1023 - step) : step;
    const float* xr = xf + ((size_t)rowc * 1024 + tn) * 512 + ako;
    #pragma unroll
    for (int kt = 0; kt < 16; ++kt) {
      short8v ax = cvtx8(xr + kt * 32);
      acc0 = __builtin_amdgcn_mfma_f32_16x16x32_bf16(ax, bih[0][kt], acc0, 0, 0, 0);
      acc1 = __builtin_amdgcn_mfma_f32_16x16x32_bf16(ax, bih[1][kt], acc1, 0, 0, 0);
    }
  }
  // h-projection: h col `step` (written by previous launch; col 0 zeroed)
  {
    const u16* hr = hsb + ((size_t)step * 8 + rowc) * 512 + ako;
    #pragma unroll
    for (int kt = 0; kt < 16; ++kt) {
      short8v ah = *(const short8v*)(hr + kt * 32);
      acc0 = __builtin_amdgcn_mfma_f32_16x16x32_bf16(ah, bhh[0][kt], acc0, 0, 0, 0);
      acc1 = __builtin_amdgcn_mfma_f32_16x16x32_bf16(ah, bhh[1][kt], acc1, 0, 0, 0);
    }
  }

  // route z to LDS: D row m=(lane>>4)*4+r (rows<8 live in lanes<32), col=lane&15
  if (lane < 32) {
    #pragma unroll
    for (int r = 0; r < 4; ++r) {
      const int brow = (lane >> 4) * 4 + r;
      zL[wid * 256 + brow * 32 + (lane & 15)]      = acc0[r];
      zL[wid * 256 + brow * 32 + 16 + (lane & 15)] = acc1[r];
    }
  }
  __syncthreads();

  // gate math, one (b,jj) per thread; c in global f32 state (ws)
  {
    const int cb = tid >> 5;
    const int cj = tid & 31;
    float zi = zL[0 * 256 + cb * 32 + cj] + bias[0 * 512 + jbase + cj];
    float zf = zL[1 * 256 + cb * 32 + cj] + bias[1 * 512 + jbase + cj];
    float zg = zL[2 * 256 + cb * 32 + cj] + bias[2 * 512 + jbase + cj];
    float zo = zL[3 * 256 + cb * 32 + cj] + bias[3 * 512 + jbase + cj];
    float si = 1.f / (1.f + __expf(-zi));
    float sf = 1.f / (1.f + __expf(-zf));
    float so = 1.f / (1.f + __expf(-zo));
    float ag = fabsf(zg); float eg = __expf(-2.f * ag);
    float tg = (1.f - eg) / (1.f + eg); tg = copysignf(tg, zg);
    float* cp = csb + dir * 4096 + cb * 512 + jbase + cj;
    float c_state = (step == 0) ? 0.f : *cp;
    c_state = sf * c_state + si * tg;
    *cp = c_state;
    float ac = fabsf(c_state); float ec = __expf(-2.f * ac);
    float tc = (1.f - ec) / (1.f + ec); tc = copysignf(tc, c_state);
    float h = so * tc;
    hsb[((size_t)(step + 1) * 8 + cb) * 512 + jbase + cj] = f2bf(h);
    if (step == 1023) {
      out[OUT_HN + dir * 4096 + cb * 512 + jbase + cj] = h;
      out[OUT_CN + dir * 4096 + cb * 512 + jbase + cj] = c_state;
    }
  }
}

// Neighbor-average epilogue. One block per (b, s), s in [1,1022].
// padded[b][t][c]: c<512 -> hsb0 col t+1 ; c>=512 -> hsb1 col 1024-t.
// *** order is int32 on device (harness converts ALL integer inputs to int) ***
__global__ void k_combine(const u16* __restrict__ hsb0, const u16* __restrict__ hsb1,
                          const int* __restrict__ cidx, const int* __restrict__ cmask,
                          const int* __restrict__ order, float* __restrict__ out)
{
  const int tid = threadIdx.x;
  const int b = blockIdx.x / 1022;
  const int s = 1 + (blockIdx.x % 1022);
  __shared__ int sidx[8];
  __shared__ float smask[8];
  __shared__ int rsh;
  if (tid == 0) rsh = order[b];
  __syncthreads();
  const int r = rsh;
  if (tid < 8) {
    size_t base = ((size_t)r * 1024 + s) * 8 + tid;
    sidx[tid] = cidx[base];
    smask[tid] = (float)cmask[base];
  }
  __syncthreads();
  float cnt = 0.f;
  #pragma unroll
  for (int k = 0; k < 8; ++k) cnt += smask[k];
  const float inv = 1.f / (1.f + cnt);

  const int col0 = tid * 4;
  const bool isF = col0 < 512;
  const int cloc = isF ? col0 : col0 - 512;
  const u16* hb = isF ? hsb0 : hsb1;

  float v0, v1, v2, v3;
  {
    size_t ci2 = isF ? (size_t)(s + 1) : (size_t)(1024 - s);
    ushort4 q = *(const ushort4*)(hb + (ci2 * 8 + b) * 512 + cloc);
    v0 = bf2f(q.x); v1 = bf2f(q.y); v2 = bf2f(q.z); v3 = bf2f(q.w);
  }
  #pragma unroll
  for (int k = 0; k < 8; ++k) {
    float m = smask[k];
    if (m != 0.f) {
      int sp = sidx[k];
      size_t ci2 = isF ? (size_t)(sp + 1) : (size_t)(1024 - sp);
      ushort4 q = *(const ushort4*)(hb + (ci2 * 8 + b) * 512 + cloc);
      v0 += m * bf2f(q.x); v1 += m * bf2f(q.y); v2 += m * bf2f(q.z); v3 += m * bf2f(q.w);
    }
  }
  size_t ob = ((size_t)r * 1022 + (s - 1)) * 1024 + col0;
  float4 ov; ov.x = v0 * inv; ov.y = v1 * inv; ov.z = v2 * inv; ov.w = v3 * inv;
  *(float4*)(out + ob) = ov;
}

extern "C" void kernel_launch(void* const* d_in, const int* in_sizes, int n_in,
                              void* d_out, int out_size, void* d_ws, size_t ws_size,
                              hipStream_t stream)
{
  const float* x      = (const float*)d_in[0];
  const int*   cidx   = (const int*)d_in[1];
  const int*   cmask  = (const int*)d_in[2];
  const int*   order  = (const int*)d_in[3];   // int64 in reference -> int32 on device
  const float* wihf = (const float*)d_in[4];
  const float* whhf = (const float*)d_in[5];
  const float* bf   = (const float*)d_in[6];
  const float* wihb = (const float*)d_in[7];
  const float* whhb = (const float*)d_in[8];
  const float* bb   = (const float*)d_in[9];
  float* out = (float*)d_out;

  char* ws = (char*)d_ws;
  u16* WIH0 = (u16*)(ws + WS_WIH0);
  u16* WIH1 = (u16*)(ws + WS_WIH1);
  u16* WHH0 = (u16*)(ws + WS_WHH0);
  u16* WHH1 = (u16*)(ws + WS_WHH1);
  u16* HSB0 = (u16*)(ws + WS_HSB0);
  u16* HSB1 = (u16*)(ws + WS_HSB1);
  float* CSB = (float*)(ws + WS_CSB);

  hipLaunchKernelGGL(k_f2bf, dim3(256), dim3(256), 0, stream, wihf, WIH0, 2048 * 512);
  hipLaunchKernelGGL(k_f2bf, dim3(256), dim3(256), 0, stream, wihb, WIH1, 2048 * 512);
  hipLaunchKernelGGL(k_f2bf, dim3(256), dim3(256), 0, stream, whhf, WHH0, 2048 * 512);
  hipLaunchKernelGGL(k_f2bf, dim3(256), dim3(256), 0, stream, whhb, WHH1, 2048 * 512);
  hipLaunchKernelGGL(k_zero, dim3(32), dim3(256), 0, stream, HSB0, HSB1, CSB);

  for (int t = 0; t < 1024; ++t) {
    hipLaunchKernelGGL(k_step, dim3(32), dim3(256), 0, stream,
                       x, WIH0, WIH1, WHH0, WHH1, bf, bb, HSB0, HSB1, CSB, out, t);
  }

  hipLaunchKernelGGL(k_combine, dim3(8 * 1022), dim3(256), 0, stream,
                     HSB0, HSB1, cidx, cmask, order, out);
}

// Round 10
// 10712.810 us; speedup vs baseline: 1.3640x; 1.3640x over previous
//
#include <hip/hip_runtime.h>
#include <stdint.h>

typedef unsigned short u16;
typedef __attribute__((ext_vector_type(8))) short short8v;
typedef __attribute__((ext_vector_type(4))) float f32x4;

// output layout (floats): out(8,1022,1024) | h_n(2,8,512) | c_n(2,8,512)
#define OUT_HN   8372224
#define OUT_CN   8380416

// ws layout (bytes) — total 25,182,464 B (R9 proved >=25.2 MB usable)
#define WS_WIH0  0
#define WS_WIH1  (WS_WIH0 + 2097152)
#define WS_WHH0  (WS_WIH1 + 2097152)
#define WS_WHH1  (WS_WHH0 + 2097152)
#define WS_HSB0  (WS_WHH1 + 2097152)        // 1025*8*512 bf16 = 8,396,800 B
#define WS_HSB1  (WS_HSB0 + 8396800)
#define WS_FLAGS (WS_HSB1 + 8396800)        // 64 * u32

__device__ __forceinline__ u16 f2bf(float f) {
  uint32_t u = __float_as_uint(f);
  u += 0x7FFFu + ((u >> 16) & 1u);
  return (u16)(u >> 16);
}
__device__ __forceinline__ float bf2f(u16 v) {
  return __uint_as_float(((uint32_t)v) << 16);
}
__device__ __forceinline__ short8v cvtx8(const float* p) {
  float4 a = *(const float4*)p;
  float4 b = *(const float4*)(p + 4);
  short8v r;
  r[0] = (short)f2bf(a.x); r[1] = (short)f2bf(a.y);
  r[2] = (short)f2bf(a.z); r[3] = (short)f2bf(a.w);
  r[4] = (short)f2bf(b.x); r[5] = (short)f2bf(b.y);
  r[6] = (short)f2bf(b.z); r[7] = (short)f2bf(b.w);
  return r;
}

__global__ void k_f2bf(const float* __restrict__ src, u16* __restrict__ dst, int n) {
  int i = blockIdx.x * blockDim.x + threadIdx.x;
  int stride = gridDim.x * blockDim.x;
  for (; i < n; i += stride) dst[i] = f2bf(src[i]);
}

__global__ void k_init(uint32_t* flags) {
  if (threadIdx.x < 64) flags[threadIdx.x] = 0;
}

// Persistent bidirectional LSTM. grid = 32 blocks x 256 threads.
// blocks 0..15: forward, 16..31: backward. Each WG owns 32 hidden units.
// Wave w = gate w (i,f,g,o). W_ih/W_hh MFMA B-fragments resident in ~256
// VGPRs (loaded once). h broadcast via bf16 hsb[(S+1)][8][512] through LLC.
// Per-step barrier: publisher agent-scope fetch_add RMW (executes at the
// coherence point), pollers agent-scope acquire loads + acquire fence.
// Bounded spin: a broken handoff degrades to a wrong answer, not a hang.
__launch_bounds__(256, 1)
__global__ void k_lstm(const float* __restrict__ xf,
                       const u16* __restrict__ wih0, const u16* __restrict__ wih1,
                       const u16* __restrict__ whh0, const u16* __restrict__ whh1,
                       const float* __restrict__ bias0, const float* __restrict__ bias1,
                       u16* hsb0, u16* hsb1, float* out, uint32_t* flags)
{
  const int tid  = threadIdx.x;
  const int wid  = tid >> 6;     // wave = gate
  const int lane = tid & 63;
  const int dir  = blockIdx.x >> 4;
  const int wg   = blockIdx.x & 15;
  const int jbase = wg * 32;

  const u16*  wih  = dir ? wih1  : wih0;
  const u16*  whh  = dir ? whh1  : whh0;
  const float* bias = dir ? bias1 : bias0;
  u16* hsb = dir ? hsb1 : hsb0;
  uint32_t* fl = flags + dir * 16;

  __shared__ float zL[4 * 8 * 32];   // [gate][b][jj]

  // B-fragments: lane holds W[row = g*512 + jbase + nt*16 + (lane&15)]
  //                          [k = kt*32 + (lane>>4)*8 .. +8]
  short8v bih[2][16], bhh[2][16];
  {
    const int rr = lane & 15;
    const int ko = (lane >> 4) * 8;
    #pragma unroll
    for (int nt = 0; nt < 2; ++nt) {
      const int row = wid * 512 + jbase + nt * 16 + rr;
      #pragma unroll
      for (int kt = 0; kt < 16; ++kt) {
        bih[nt][kt] = *(const short8v*)(wih + (size_t)row * 512 + kt * 32 + ko);
        bhh[nt][kt] = *(const short8v*)(whh + (size_t)row * 512 + kt * 32 + ko);
      }
    }
  }

  // gate-phase ownership: thread -> (b, jj)
  const int cb = tid >> 5;
  const int cj = tid & 31;
  float c_state = 0.f;
  const float bz0 = bias[0 * 512 + jbase + cj];
  const float bz1 = bias[1 * 512 + jbase + cj];
  const float bz2 = bias[2 * 512 + jbase + cj];
  const float bz3 = bias[3 * 512 + jbase + cj];

  // A-fragment: row = lane&7 (lanes 8..15 duplicate rows 0..7; their D rows
  // are never stored), k = (lane>>4)*8
  const int rowc = lane & 7;
  const int ako  = (lane >> 4) * 8;

  const f32x4 fzero = {0.f, 0.f, 0.f, 0.f};
  f32x4 acc0 = fzero, acc1 = fzero;

  // x-projection for step 0 (no h dependency); x read f32 from d_in
  {
    const int t0 = dir ? 1023 : 0;
    const float* xr = xf + ((size_t)rowc * 1024 + t0) * 512 + ako;
    #pragma unroll
    for (int kt = 0; kt < 16; ++kt) {
      short8v ax = cvtx8(xr + kt * 32);
      acc0 = __builtin_amdgcn_mfma_f32_16x16x32_bf16(ax, bih[0][kt], acc0, 0, 0, 0);
      acc1 = __builtin_amdgcn_mfma_f32_16x16x32_bf16(ax, bih[1][kt], acc1, 0, 0, 0);
    }
  }

  for (int step = 0; step < 1024; ++step) {
    if (step > 0) {
      // wait for all WGs of my direction to have published h col `step`
      if (tid < 16) {
        int guard = 0;
        while (__hip_atomic_load(&fl[tid], __ATOMIC_ACQUIRE, __HIP_MEMORY_SCOPE_AGENT)
               < (uint32_t)step && ++guard < (1 << 14)) { }
      }
      __syncthreads();
      __builtin_amdgcn_fence(__ATOMIC_ACQUIRE, "agent");
      // h-part MFMAs (critical path)
      const u16* hr = hsb + ((size_t)step * 8 + rowc) * 512 + ako;
      #pragma unroll
      for (int kt = 0; kt < 16; ++kt) {
        short8v ah = *(const short8v*)(hr + kt * 32);
        acc0 = __builtin_amdgcn_mfma_f32_16x16x32_bf16(ah, bhh[0][kt], acc0, 0, 0, 0);
        acc1 = __builtin_amdgcn_mfma_f32_16x16x32_bf16(ah, bhh[1][kt], acc1, 0, 0, 0);
      }
    }
    // route z to LDS: D row m=(lane>>4)*4+r (rows<8 live in lanes<32), col=lane&15
    if (lane < 32) {
      #pragma unroll
      for (int r = 0; r < 4; ++r) {
        const int brow = (lane >> 4) * 4 + r;
        zL[wid * 256 + brow * 32 + (lane & 15)]      = acc0[r];
        zL[wid * 256 + brow * 32 + 16 + (lane & 15)] = acc1[r];
      }
    }
    __syncthreads();
    // gate math, one (b,jj) per thread; c stays in a register
    {
      float zi = zL[0 * 256 + cb * 32 + cj] + bz0;
      float zf = zL[1 * 256 + cb * 32 + cj] + bz1;
      float zg = zL[2 * 256 + cb * 32 + cj] + bz2;
      float zo = zL[3 * 256 + cb * 32 + cj] + bz3;
      float si = 1.f / (1.f + __expf(-zi));
      float sf = 1.f / (1.f + __expf(-zf));
      float so = 1.f / (1.f + __expf(-zo));
      float ag = fabsf(zg); float eg = __expf(-2.f * ag);
      float tg = (1.f - eg) / (1.f + eg); tg = copysignf(tg, zg);
      c_state = sf * c_state + si * tg;
      float ac = fabsf(c_state); float ec = __expf(-2.f * ac);
      float tc = (1.f - ec) / (1.f + ec); tc = copysignf(tc, c_state);
      float h = so * tc;
      hsb[((size_t)(step + 1) * 8 + cb) * 512 + jbase + cj] = f2bf(h);
      if (step == 1023) {
        out[OUT_HN + dir * 4096 + cb * 512 + jbase + cj] = h;
        out[OUT_CN + dir * 4096 + cb * 512 + jbase + cj] = c_state;
      }
    }
    __syncthreads();  // implies vmcnt(0): this WG's h stores are in L2
    if (tid == 0) {
      // RMW executes at the coherence point; release orders prior stores
      __hip_atomic_fetch_add(&fl[wg], 1u, __ATOMIC_RELEASE, __HIP_MEMORY_SCOPE_AGENT);
    }
    // x-projection for next step — off the critical path (after publish)
    if (step < 1023) {
      acc0 = fzero; acc1 = fzero;
      const int tn = dir ? (1022 - step) : (step + 1);
      const float* xr = xf + ((size_t)rowc * 1024 + tn) * 512 + ako;
      #pragma unroll
      for (int kt = 0; kt < 16; ++kt) {
        short8v ax = cvtx8(xr + kt * 32);
        acc0 = __builtin_amdgcn_mfma_f32_16x16x32_bf16(ax, bih[0][kt], acc0, 0, 0, 0);
        acc1 = __builtin_amdgcn_mfma_f32_16x16x32_bf16(ax, bih[1][kt], acc1, 0, 0, 0);
      }
    }
  }
}

// Neighbor-average epilogue — R9-proven version (order is int32 on device).
// One block per (b, s), s in [1,1022].
// padded[b][t][c]: c<512 -> hsb0 col t+1 ; c>=512 -> hsb1 col 1024-t.
__global__ void k_combine(const u16* __restrict__ hsb0, const u16* __restrict__ hsb1,
                          const int* __restrict__ cidx, const int* __restrict__ cmask,
                          const int* __restrict__ order, float* __restrict__ out)
{
  const int tid = threadIdx.x;
  const int b = blockIdx.x / 1022;
  const int s = 1 + (blockIdx.x % 1022);
  __shared__ int sidx[8];
  __shared__ float smask[8];
  __shared__ int rsh;
  if (tid == 0) rsh = order[b];
  __syncthreads();
  const int r = rsh;
  if (tid < 8) {
    size_t base = ((size_t)r * 1024 + s) * 8 + tid;
    sidx[tid] = cidx[base];
    smask[tid] = (float)cmask[base];
  }
  __syncthreads();
  float cnt = 0.f;
  #pragma unroll
  for (int k = 0; k < 8; ++k) cnt += smask[k];
  const float inv = 1.f / (1.f + cnt);

  const int col0 = tid * 4;
  const bool isF = col0 < 512;
  const int cloc = isF ? col0 : col0 - 512;
  const u16* hb = isF ? hsb0 : hsb1;

  float v0, v1, v2, v3;
  {
    size_t ci2 = isF ? (size_t)(s + 1) : (size_t)(1024 - s);
    ushort4 q = *(const ushort4*)(hb + (ci2 * 8 + b) * 512 + cloc);
    v0 = bf2f(q.x); v1 = bf2f(q.y); v2 = bf2f(q.z); v3 = bf2f(q.w);
  }
  #pragma unroll
  for (int k = 0; k < 8; ++k) {
    float m = smask[k];
    if (m != 0.f) {
      int sp = sidx[k];
      size_t ci2 = isF ? (size_t)(sp + 1) : (size_t)(1024 - sp);
      ushort4 q = *(const ushort4*)(hb + (ci2 * 8 + b) * 512 + cloc);
      v0 += m * bf2f(q.x); v1 += m * bf2f(q.y); v2 += m * bf2f(q.z); v3 += m * bf2f(q.w);
    }
  }
  size_t ob = ((size_t)r * 1022 + (s - 1)) * 1024 + col0;
  float4 ov; ov.x = v0 * inv; ov.y = v1 * inv; ov.z = v2 * inv; ov.w = v3 * inv;
  *(float4*)(out + ob) = ov;
}

extern "C" void kernel_launch(void* const* d_in, const int* in_sizes, int n_in,
                              void* d_out, int out_size, void* d_ws, size_t ws_size,
                              hipStream_t stream)
{
  const float* x      = (const float*)d_in[0];
  const int*   cidx   = (const int*)d_in[1];
  const int*   cmask  = (const int*)d_in[2];
  const int*   order  = (const int*)d_in[3];   // int64 in reference -> int32 on device
  const float* wihf = (const float*)d_in[4];
  const float* whhf = (const float*)d_in[5];
  const float* bf   = (const float*)d_in[6];
  const float* wihb = (const float*)d_in[7];
  const float* whhb = (const float*)d_in[8];
  const float* bb   = (const float*)d_in[9];
  float* out = (float*)d_out;

  char* ws = (char*)d_ws;
  u16* WIH0 = (u16*)(ws + WS_WIH0);
  u16* WIH1 = (u16*)(ws + WS_WIH1);
  u16* WHH0 = (u16*)(ws + WS_WHH0);
  u16* WHH1 = (u16*)(ws + WS_WHH1);
  u16* HSB0 = (u16*)(ws + WS_HSB0);
  u16* HSB1 = (u16*)(ws + WS_HSB1);
  uint32_t* FLAGS = (uint32_t*)(ws + WS_FLAGS);

  hipLaunchKernelGGL(k_f2bf, dim3(256), dim3(256), 0, stream, wihf, WIH0, 2048 * 512);
  hipLaunchKernelGGL(k_f2bf, dim3(256), dim3(256), 0, stream, wihb, WIH1, 2048 * 512);
  hipLaunchKernelGGL(k_f2bf, dim3(256), dim3(256), 0, stream, whhf, WHH0, 2048 * 512);
  hipLaunchKernelGGL(k_f2bf, dim3(256), dim3(256), 0, stream, whhb, WHH1, 2048 * 512);
  hipLaunchKernelGGL(k_init, dim3(1), dim3(64), 0, stream, FLAGS);
  hipLaunchKernelGGL(k_lstm, dim3(32), dim3(256), 0, stream,
                     x, WIH0, WIH1, WHH0, WHH1, bf, bb, HSB0, HSB1, out, FLAGS);
  hipLaunchKernelGGL(k_combine, dim3(8 * 1022), dim3(256), 0, stream,
                     HSB0, HSB1, cidx, cmask, order, out);
}